// Round 4
// baseline (394.340 us; speedup 1.0000x reference)
//
#include <hip/hip_runtime.h>
#include <math.h>

// Problem constants (fixed by setup_inputs)
#define B_  32
#define N_  20000
#define C_  8
#define E_  512
#define H_  8
#define SCALE 0.125f    // 1/sqrt(64)
#define UNSC  9.765625e-4f   // 1/1024 = 1/(32*32) operand pre-scale undo

#define CHUNK 1024
#define NCH   20       // ceil(20000/1024) (top-k chunking)
#define NC3   157      // ceil(20000/128)  (GEMM n-chunks, BN=128)
#define NCG   20       // ceil(NC3/8) nc-groups for XCD swizzle
#define SSZ ((size_t)B_ * H_ * N_)   // per-class S floats (256*20000)

typedef __attribute__((ext_vector_type(8))) _Float16 h8_t;  // 8 fp16 (4 VGPRs)
typedef __attribute__((ext_vector_type(8))) short   s8_t;   // 8 shorts (16 B)
typedef __attribute__((ext_vector_type(4))) float f32x4;    // 16x16 MFMA acc

#define MFMAH(a, b, c) __builtin_amdgcn_mfma_f32_16x16x32_f16(a, b, c, 0, 0, 0)

// async global->LDS, 16B per lane, wave-uniform LDS base + lane*16
#define GLOAD_LDS16(g, l)                                              \
    __builtin_amdgcn_global_load_lds(                                  \
        (const __attribute__((address_space(1))) unsigned int*)(g),    \
        (__attribute__((address_space(3))) unsigned int*)(l), 16, 0, 0)

// RNE round-to-fp16, returns bit pattern + rounded value
__device__ inline unsigned short f16_round(float x, float& fv) {
    _Float16 h = (_Float16)x;
    fv = (float)h;
    union { _Float16 hh; unsigned short us; } u;
    u.hh = h;
    return u.us;
}

// ---------------------------------------------------------------------------
// K1a: q(c,b,f) = sum_e x(b,e) * Wq[c][f,e] + bq[c][f]
// ---------------------------------------------------------------------------
__global__ __launch_bounds__(256) void k_q2(
        const float* __restrict__ x, const float* __restrict__ Wq,
        const float* __restrict__ bq, float* __restrict__ q) {
    int ft = blockIdx.x, c = blockIdx.y;
    int f0 = ft * 8;
    __shared__ float wsm[8][66];
    __shared__ float xs[32][66];
    int tid = threadIdx.x;
    int b = tid & 31, fs = tid >> 5;
    float acc = 0.f;
    const float* W = Wq + (size_t)c * E_ * E_;
    for (int k0 = 0; k0 < E_; k0 += 64) {
        __syncthreads();
        for (int i = tid; i < 512; i += 256)
            wsm[i >> 6][i & 63] = W[(size_t)(f0 + (i >> 6)) * E_ + k0 + (i & 63)];
        for (int i = tid; i < 2048; i += 256)
            xs[i >> 6][i & 63] = x[(size_t)(i >> 6) * E_ + k0 + (i & 63)];
        __syncthreads();
        #pragma unroll
        for (int kk = 0; kk < 64; ++kk)
            acc += xs[b][kk] * wsm[fs][kk];
    }
    q[((size_t)c * B_ + b) * E_ + f0 + fs] = acc + bq[c * E_ + f0 + fs];
}

// ---------------------------------------------------------------------------
// K1b (R12: fused with u2-split): u(c, m=(b*8+h), e) = sum_d q(c,b,h*64+d) *
// Wk[c][h*64+d, e], written DIRECTLY as 2 fp16 planes in 16x16x32 A-fragment
// order (the old k_split_u2 mapping):
//   m = b*8+h -> mt = m>>4, l15 = m&15; e-run e0+es*8..+7 -> ks = e>>5,
//   quad = (e&31)>>3; lane = l15 + 16*quad; one 16B store per plane.
// Eliminates the u round-trip (8 MB) and a kernel launch.
// ---------------------------------------------------------------------------
#define U2P ((size_t)C_ * 16 * 16 * 512)   // 1,048,576 shorts per plane

__global__ __launch_bounds__(256) void k_u2(
        const float* __restrict__ q, const float* __restrict__ Wk,
        const float* __restrict__ bk, short* __restrict__ u2,
        float* __restrict__ qb) {
    int et = blockIdx.x, h = blockIdx.y, c = blockIdx.z;
    int e0 = et * 64;
    __shared__ float qs[32][66];
    __shared__ float wk[64][66];
    int tid = threadIdx.x;
    int b = tid & 31, es = tid >> 5;
    for (int i = tid; i < 2048; i += 256)
        qs[i >> 6][i & 63] = q[((size_t)c * B_ + (i >> 6)) * E_ + h * 64 + (i & 63)];
    const float* W = Wk + (size_t)c * E_ * E_ + (size_t)(h * 64) * E_;
    for (int i = tid; i < 4096; i += 256)
        wk[i >> 6][i & 63] = W[(size_t)(i >> 6) * E_ + e0 + (i & 63)];
    __syncthreads();
    float acc[8] = {};
    for (int d = 0; d < 64; ++d) {
        float qv = qs[b][d];
        #pragma unroll
        for (int j = 0; j < 8; ++j)
            acc[j] += qv * wk[d][es * 8 + j];
    }
    // direct fragment-order store (old k_split_u2 math, u round-trip removed)
    int m   = b * 8 + h;
    int e0s = e0 + es * 8;
    int ks  = e0s >> 5, quad = (e0s & 31) >> 3;
    int lane = (m & 15) + 16 * quad;
    int mt  = m >> 4;
    size_t base = ((((size_t)c * 16 + mt) * 16 + ks) * 512) + (size_t)lane * 8;
    s8_t vh, vm;
    #pragma unroll
    for (int j = 0; j < 8; ++j) {
        float xv = acc[j] * 32.0f, fh, fm;
        vh[j] = (short)f16_round(xv, fh);
        vm[j] = (short)f16_round(xv - fh, fm);
    }
    *(s8_t*)(u2 + base)       = vh;
    *(s8_t*)(u2 + U2P + base) = vm;
    if (et == 0 && es == 0) {
        float s = 0.f;
        const float* bkr = bk + c * E_ + h * 64;
        for (int d = 0; d < 64; ++d) s += qs[b][d] * bkr[d];
        qb[c * 256 + b * 8 + h] = s;
    }
}

// ---------------------------------------------------------------------------
// Split A*32 into 2 fp16 planes, tiled per (nchunk 128, kstep 32) with the
// R5 within-row 16B-chunk swizzle -> zero LDS conflicts for B-frag reads.
// ---------------------------------------------------------------------------
__global__ void k_split_A2(const float* __restrict__ A, short* __restrict__ A2t) {
    int nc = blockIdx.x, ks = blockIdx.y;
    int tid = threadIdx.x;
    int n = tid >> 1, kg = (tid & 1) * 2;   // logical chunks kg, kg+1 of 4
    int gn = nc * 128 + n;
    const float* ap = A + (size_t)gn * 512 + ks * 32 + kg * 8;
    s8_t vh[2], vm[2];
    #pragma unroll
    for (int g = 0; g < 2; ++g)
        #pragma unroll
        for (int j = 0; j < 8; ++j) {
            float x = (gn < N_) ? ap[g * 8 + j] * 32.0f : 0.f;
            float fh, fm;
            vh[g][j] = (short)f16_round(x, fh);
            vm[g][j] = (short)f16_round(x - fh, fm);
        }
    short* outp = A2t + ((size_t)nc * 16 + ks) * 8192 + n * 32;
    #pragma unroll
    for (int g = 0; g < 2; ++g) {
        int p = ((kg + g) + (n >> 1)) & 3;
        *(s8_t*)(outp + p * 8)        = vh[g];
        *(s8_t*)(outp + 4096 + p * 8) = vm[g];
    }
}

// ---------------------------------------------------------------------------
// Main: S(m,n) = member ? exp(SCALE*(dot/1024 + qb)) : 0, 3-product fp16x2
// (hh, hm, mh) via 16x16x32 f16 MFMA.
//
// R11 proved occupancy is the lever (3 blocks/CU: 147->123 us, MfmaUtil 48).
// R12: counters show 64 arch VGPR + 64 AGPR = 128/wave exactly -> 4 waves/
// SIMD admissible; LDS 33.8 KB x4 = 135 KB < 160 KB. Bump launch_bounds to
// (256,4) for the 4th resident block. Structure otherwise identical to R11
// (schedule experiments R9/R10 were perfect nulls; TLP is what pays).
// ---------------------------------------------------------------------------
__global__ __launch_bounds__(256, 4) void k_scores_mfma(
        const short* __restrict__ u2, const short* __restrict__ A2t,
        const float* __restrict__ qb, const int* __restrict__ mask,
        float* __restrict__ S, float* __restrict__ Zpart, int c0, int CB) {
    __shared__ __align__(16) short As[16384];   // one 32 KB ks2-tile (2 kh)
    __shared__ float sQb[128];
    __shared__ int   sMask[128];
    int bx = blockIdx.x;
    int x     = bx & 7;
    int rest  = bx >> 3;
    int mh    = rest & 1;          // m-half: rows [mh*128, mh*128+128)
    int rest2 = rest >> 1;
    int z     = rest2 % CB;
    int g     = rest2 / CB;
    int nc    = g * 8 + x;
    if (nc >= NC3) return;
    int c  = c0 + z;
    int tid = threadIdx.x;
    int lane = tid & 63, w = tid >> 6;
    int quad = lane >> 4, l15 = lane & 15;
    int n0 = nc * 128;

    if (tid < 128) {
        sQb[tid] = qb[c * 256 + mh * 128 + tid];
        int n = n0 + tid;
        sMask[tid] = (n < N_) ? mask[(size_t)n * C_ + c] : 0;
    }

    f32x4 acc[2][8];   // [mt][nt] — wave owns 32 rows x 128 cols
    #pragma unroll
    for (int i = 0; i < 2; ++i)
        #pragma unroll
        for (int j = 0; j < 8; ++j)
            acc[i][j] = (f32x4){0.f, 0.f, 0.f, 0.f};

    const char* tb = (const char*)A2t + (size_t)nc * 262144;

    for (int ks2 = 0; ks2 < 8; ++ks2) {
        __syncthreads();   // all waves done reading As (and covers sQb/sMask)
        // async DMA this ks2's 32 KB (two 16 KB kh tiles): 32 segs of 1024 B
        const char* src = tb + (size_t)ks2 * 32768;
        #pragma unroll
        for (int t = 0; t < 8; ++t) {
            int seg = w * 8 + t;
            GLOAD_LDS16(src + (size_t)seg * 1024 + lane * 16,
                        (char*)As + seg * 1024);
        }
        __syncthreads();   // compiler drains vmcnt(0) before barrier

        #pragma unroll
        for (int kh = 0; kh < 2; ++kh) {
            int ks = ks2 * 2 + kh;
            const short* Ab = As + kh * 8192;
            // A-fragments (u2): 4 global 16B loads, L2/LLC-resident
            h8_t af[2][2];
            #pragma unroll
            for (int mt = 0; mt < 2; ++mt) {
                int mtg = mh * 8 + w * 2 + mt;
                size_t ub = ((((size_t)c * 16 + mtg) * 16 + ks) * 512)
                            + (size_t)lane * 8;
                af[mt][0] = *(const h8_t*)(u2 + ub);
                af[mt][1] = *(const h8_t*)(u2 + U2P + ub);
            }
            // two nt-halves; sched_barrier caps b-frag hoisting (reg budget)
            #pragma unroll
            for (int half = 0; half < 2; ++half) {
                __builtin_amdgcn_sched_barrier(0);
                #pragma unroll
                for (int q4 = 0; q4 < 4; ++q4) {
                    int nt = half * 4 + q4;
                    int r = nt * 16 + l15;
                    const short* bp = Ab + r * 32 + ((quad + (r >> 1)) & 3) * 8;
                    h8_t b0 = *(const h8_t*)bp;
                    h8_t b1 = *(const h8_t*)(bp + 4096);
                    #pragma unroll
                    for (int mt = 0; mt < 2; ++mt) {
                        f32x4 a = acc[mt][nt];
                        a = MFMAH(af[mt][0], b0, a);   // hh
                        a = MFMAH(af[mt][0], b1, a);   // hm
                        a = MFMAH(af[mt][1], b0, a);   // mh
                        acc[mt][nt] = a;
                    }
                }
            }
        }
    }

    // Epilogue: unscale + bias + mask + exp, write S, fused deterministic
    // row-sums.  C/D: col = lane&15, row = quad*4 + r (m89/m91).
    float* Sc = S + (size_t)z * SSZ;
    #pragma unroll
    for (int mt = 0; mt < 2; ++mt) {
        float rs[4] = {0.f, 0.f, 0.f, 0.f};
        #pragma unroll
        for (int nt = 0; nt < 8; ++nt) {
            int nl = nt * 16 + l15;
            int n = n0 + nl;
            int mem = sMask[nl];
            #pragma unroll
            for (int r = 0; r < 4; ++r) {
                int ml = w * 32 + mt * 16 + quad * 4 + r;   // local row in half
                float sc = SCALE * (acc[mt][nt][r] * UNSC + sQb[ml]);
                float ev = mem ? __expf(sc) : 0.f;
                rs[r] += ev;
                if (n < N_) Sc[(size_t)(mh * 128 + ml) * N_ + n] = ev;
            }
        }
        #pragma unroll
        for (int r = 0; r < 4; ++r) {
            float v = rs[r];
            v += __shfl_xor(v, 1); v += __shfl_xor(v, 2);
            v += __shfl_xor(v, 4); v += __shfl_xor(v, 8);
            if (l15 == 0) {
                int ml = w * 32 + mt * 16 + quad * 4 + r;
                Zpart[((size_t)nc * C_ + c) * 256 + mh * 128 + ml] = v;
            }
        }
    }
}

// ---------------------------------------------------------------------------
// Z(c,m) = sum_nc Zpart(nc,c,m). grid = CB blocks x 256 thr.
// ---------------------------------------------------------------------------
__global__ void k_zsum(const float* __restrict__ Zpart, float* __restrict__ Z, int c0) {
    int c = c0 + blockIdx.x;
    int i = c * 256 + threadIdx.x;
    float s = 0.f;
    for (int nc = 0; nc < NC3; ++nc) s += Zpart[(size_t)nc * (C_ * 256) + i];
    Z[i] = s;
}

// ---------------------------------------------------------------------------
// K3: fused head-average + chunk-local top-ns. grid (NCH, B, CB).
// R12: barrier-free selection rounds. Each wave owns a disjoint 256-float
// slice; after the 64-lane butterfly ALL lanes hold the wave winner, so
// removal needs no LDS/broadcast/syncthreads. 5 rounds of pure shfl, then
// one barrier + serial 4*ns -> ns merge on thread 0 (tie: low index wins,
// exactly as before). Removes ~15 block barriers per block.
// ---------------------------------------------------------------------------
__global__ __launch_bounds__(256) void k_topk1(
        const float* __restrict__ S, const float* __restrict__ Z,
        float2* __restrict__ cand, int c0, int ns) {
    int chunk = blockIdx.x, b = blockIdx.y, z = blockIdx.z;
    const float* Sc = S + (size_t)z * SSZ;
    int tid = threadIdx.x;
    __shared__ float zr[H_];
    if (tid < H_) zr[tid] = 1.0f / Z[(c0 + z) * (B_ * H_) + b * H_ + tid];
    __syncthreads();
    int n0 = chunk * CHUNK + tid * 4;
    bool valid = n0 < N_;          // N_ % 4 == 0: float4 fully valid or not
    float4 a = make_float4(0.f, 0.f, 0.f, 0.f);
    if (valid) {
        #pragma unroll
        for (int h = 0; h < H_; ++h) {
            const float4 sv = *(const float4*)&Sc[(size_t)(b * H_ + h) * N_ + n0];
            float wz = zr[h];
            a.x += sv.x * wz; a.y += sv.y * wz; a.z += sv.z * wz; a.w += sv.w * wz;
        }
    }
    float v[4]; int ix[4];
    v[0] = valid ? a.x * 0.125f : -1.f;
    v[1] = valid ? a.y * 0.125f : -1.f;
    v[2] = valid ? a.z * 0.125f : -1.f;
    v[3] = valid ? a.w * 0.125f : -1.f;
    #pragma unroll
    for (int t = 0; t < 4; ++t) ix[t] = valid ? n0 + t : N_;

    __shared__ float wv[4][8];     // per-wave top-ns (ns <= 8)
    __shared__ int   wi[4][8];
    int lane = tid & 63, w = tid >> 6;
    for (int j = 0; j < ns; ++j) {
        float bv = v[0]; int bi = ix[0];
        #pragma unroll
        for (int t = 1; t < 4; ++t)
            if (v[t] > bv || (v[t] == bv && ix[t] < bi)) { bv = v[t]; bi = ix[t]; }
        #pragma unroll
        for (int off = 1; off < 64; off <<= 1) {
            float ov = __shfl_xor(bv, off, 64);
            int   oi = __shfl_xor(bi, off, 64);
            if (ov > bv || (ov == bv && oi < bi)) { bv = ov; bi = oi; }
        }
        if (lane == 0) { wv[w][j] = bv; wi[w][j] = bi; }
        // all lanes hold the wave winner after the butterfly: remove locally
        #pragma unroll
        for (int t = 0; t < 4; ++t)
            if (ix[t] == bi) v[t] = -2.f;
    }
    __syncthreads();
    if (tid == 0) {
        unsigned used = 0;
        float2* cp = cand + (((size_t)z * B_ + b) * NCH + chunk) * ns;
        for (int j = 0; j < ns; ++j) {
            float fv = -4.f; int fi = N_ + 1; int fs = -1;
            for (int s2 = 0; s2 < 4 * ns; ++s2) {
                if (used & (1u << s2)) continue;
                float cv = wv[s2 >> 3][s2 & 7];   // s2 = w2*ns + t below
                int   ci = wi[s2 >> 3][s2 & 7];
                (void)cv; (void)ci;
                break;
            }
            // flat scan over [w2][t]
            for (int w2 = 0; w2 < 4; ++w2)
                for (int t = 0; t < ns; ++t) {
                    int s2 = w2 * ns + t;
                    if (used & (1u << s2)) continue;
                    float cv = wv[w2][t]; int ci = wi[w2][t];
                    if (cv > fv || (cv == fv && ci < fi)) { fv = cv; fi = ci; fs = s2; }
                }
            used |= (1u << fs);
            cp[j] = make_float2(fv, (float)fi);
        }
    }
}

// ---------------------------------------------------------------------------
// K4: merge NCH*ns candidates -> final top-ns per (b, class). grid (B, CB).
// ---------------------------------------------------------------------------
__global__ __launch_bounds__(256) void k_topk2(
        const float2* __restrict__ cand, float* __restrict__ out, int c0, int ns) {
    int b = blockIdx.x, z = blockIdx.y;
    int c = c0 + z;
    int tid = threadIdx.x;
    int ncand = NCH * ns;   // 100
    const float2* cb = cand + ((size_t)z * B_ + b) * ncand;
    float v = -3.f; int ix = N_ + 1;
    if (tid < ncand) { float2 e = cb[tid]; v = e.x; ix = (int)e.y; }
    __shared__ float sv[256];
    __shared__ int   si[256];
    __shared__ int   win;
    for (int j = 0; j < ns; ++j) {
        sv[tid] = v; si[tid] = ix;
        __syncthreads();
        for (int w = 128; w >= 1; w >>= 1) {
            if (tid < w) {
                float v2 = sv[tid + w]; int i2 = si[tid + w];
                if (v2 > sv[tid] || (v2 == sv[tid] && i2 < si[tid])) {
                    sv[tid] = v2; si[tid] = i2;
                }
            }
            __syncthreads();
        }
        if (tid == 0) {
            out[((size_t)b * C_ + c) * ns + j] = (float)si[0];
            out[(size_t)B_ * C_ * ns + ((size_t)b * C_ + c) * ns + j] = sv[0];
            win = si[0];
        }
        __syncthreads();
        if (ix == win) v = -3.f;
        __syncthreads();
    }
}

// ---------------------------------------------------------------------------
extern "C" void kernel_launch(void* const* d_in, const int* in_sizes, int n_in,
                              void* d_out, int out_size, void* d_ws, size_t ws_size,
                              hipStream_t stream) {
    const float* x    = (const float*)d_in[0];  // (B,E)
    const float* A    = (const float*)d_in[1];  // (N,E)
    const int*   mask = (const int*)  d_in[2];  // (N,C)
    const float* Wq   = (const float*)d_in[3];  // (C,E,E)
    const float* bq   = (const float*)d_in[4];  // (C,E)
    const float* Wk   = (const float*)d_in[5];  // (C,E,E)
    const float* bk   = (const float*)d_in[6];  // (C,E)
    float* out = (float*)d_out;

    int ns = out_size / (2 * B_ * C_);          // = n_samples (5)

    // Workspace carve (floats) — u buffer removed (k_u2 writes u2 directly)
    float* ws = (float*)d_ws;
    float* q     = ws;                                    // 131072
    float* qb    = q     + (size_t)C_ * B_ * E_;          // 2048
    float* Z     = qb    + (size_t)C_ * B_ * H_;          // 2048
    float* Zpart = Z     + (size_t)C_ * B_ * H_;          // NC3*8*256 = 321536
    short* u2    = (short*)(Zpart + (size_t)NC3 * C_ * 256);   // 2*1048576 shorts
    short* A2t   = u2 + 2 * U2P;                               // NC3*16*8192 shorts
    float* S     = (float*)(A2t + (size_t)NC3 * 16 * 8192);
    size_t fixedFloats = (size_t)(S - ws);

    size_t candFloats = (size_t)C_ * B_ * NCH * ns * 2;
    int CB = 8;
    while (CB > 1 &&
           (fixedFloats + (size_t)CB * SSZ + candFloats + 16) * 4 > ws_size)
        CB >>= 1;
    float2* cand = (float2*)(S + (size_t)CB * SSZ);

    k_q2<<<dim3(64, C_), 256, 0, stream>>>(x, Wq, bq, q);
    k_u2<<<dim3(8, H_, C_), 256, 0, stream>>>(q, Wk, bk, u2, qb);
    k_split_A2<<<dim3(NC3, 16), 256, 0, stream>>>(A, A2t);

    for (int c0 = 0; c0 < C_; c0 += CB) {
        // grid: (g, z, mh, x) packed; 2 m-half blocks per (nc, c)
        k_scores_mfma<<<NCG * 2 * 8 * CB, 256, 0, stream>>>(u2, A2t, qb, mask, S, Zpart, c0, CB);
        k_zsum<<<CB, 256, 0, stream>>>(Zpart, Z, c0);
        k_topk1<<<dim3(NCH, B_, CB), 256, 0, stream>>>(S, Z, cand, c0, ns);
        k_topk2<<<dim3(B_, CB), 256, 0, stream>>>(cand, out, c0, ns);
    }
}

// Round 5
// 365.600 us; speedup vs baseline: 1.0786x; 1.0786x over previous
//
#include <hip/hip_runtime.h>
#include <math.h>

// Problem constants (fixed by setup_inputs)
#define B_  32
#define N_  20000
#define C_  8
#define E_  512
#define H_  8
#define SCALE 0.125f    // 1/sqrt(64)
#define UNSC  9.765625e-4f   // 1/1024 = 1/(32*32) operand pre-scale undo

#define CHUNK 1024
#define NCH   20       // ceil(20000/1024) (top-k chunking)
#define NC3   157      // ceil(20000/128)  (GEMM n-chunks, BN=128)
#define NCG   20       // ceil(NC3/8) nc-groups for XCD swizzle
#define SSZ ((size_t)B_ * H_ * N_)   // per-class S floats (256*20000)

typedef __attribute__((ext_vector_type(8))) _Float16 h8_t;  // 8 fp16 (4 VGPRs)
typedef __attribute__((ext_vector_type(8))) short   s8_t;   // 8 shorts (16 B)
typedef __attribute__((ext_vector_type(4))) float f32x4;    // 16x16 MFMA acc

#define MFMAH(a, b, c) __builtin_amdgcn_mfma_f32_16x16x32_f16(a, b, c, 0, 0, 0)

// async global->LDS, 16B per lane, wave-uniform LDS base + lane*16
#define GLOAD_LDS16(g, l)                                              \
    __builtin_amdgcn_global_load_lds(                                  \
        (const __attribute__((address_space(1))) unsigned int*)(g),    \
        (__attribute__((address_space(3))) unsigned int*)(l), 16, 0, 0)

// RNE round-to-fp16, returns bit pattern + rounded value
__device__ inline unsigned short f16_round(float x, float& fv) {
    _Float16 h = (_Float16)x;
    fv = (float)h;
    union { _Float16 hh; unsigned short us; } u;
    u.hh = h;
    return u.us;
}

// ---------------------------------------------------------------------------
// K1a: q(c,b,f) = sum_e x(b,e) * Wq[c][f,e] + bq[c][f]
// ---------------------------------------------------------------------------
__global__ __launch_bounds__(256) void k_q2(
        const float* __restrict__ x, const float* __restrict__ Wq,
        const float* __restrict__ bq, float* __restrict__ q) {
    int ft = blockIdx.x, c = blockIdx.y;
    int f0 = ft * 8;
    __shared__ float wsm[8][66];
    __shared__ float xs[32][66];
    int tid = threadIdx.x;
    int b = tid & 31, fs = tid >> 5;
    float acc = 0.f;
    const float* W = Wq + (size_t)c * E_ * E_;
    for (int k0 = 0; k0 < E_; k0 += 64) {
        __syncthreads();
        for (int i = tid; i < 512; i += 256)
            wsm[i >> 6][i & 63] = W[(size_t)(f0 + (i >> 6)) * E_ + k0 + (i & 63)];
        for (int i = tid; i < 2048; i += 256)
            xs[i >> 6][i & 63] = x[(size_t)(i >> 6) * E_ + k0 + (i & 63)];
        __syncthreads();
        #pragma unroll
        for (int kk = 0; kk < 64; ++kk)
            acc += xs[b][kk] * wsm[fs][kk];
    }
    q[((size_t)c * B_ + b) * E_ + f0 + fs] = acc + bq[c * E_ + f0 + fs];
}

// ---------------------------------------------------------------------------
// K1b (fused with u2-split): u(c, m=(b*8+h), e) = sum_d q(c,b,h*64+d) *
// Wk[c][h*64+d, e], written DIRECTLY as 2 fp16 planes in 16x16x32 A-fragment
// order. Eliminates the u round-trip (8 MB) and a kernel launch.
// ---------------------------------------------------------------------------
#define U2P ((size_t)C_ * 16 * 16 * 512)   // 1,048,576 shorts per plane

__global__ __launch_bounds__(256) void k_u2(
        const float* __restrict__ q, const float* __restrict__ Wk,
        const float* __restrict__ bk, short* __restrict__ u2,
        float* __restrict__ qb) {
    int et = blockIdx.x, h = blockIdx.y, c = blockIdx.z;
    int e0 = et * 64;
    __shared__ float qs[32][66];
    __shared__ float wk[64][66];
    int tid = threadIdx.x;
    int b = tid & 31, es = tid >> 5;
    for (int i = tid; i < 2048; i += 256)
        qs[i >> 6][i & 63] = q[((size_t)c * B_ + (i >> 6)) * E_ + h * 64 + (i & 63)];
    const float* W = Wk + (size_t)c * E_ * E_ + (size_t)(h * 64) * E_;
    for (int i = tid; i < 4096; i += 256)
        wk[i >> 6][i & 63] = W[(size_t)(i >> 6) * E_ + e0 + (i & 63)];
    __syncthreads();
    float acc[8] = {};
    for (int d = 0; d < 64; ++d) {
        float qv = qs[b][d];
        #pragma unroll
        for (int j = 0; j < 8; ++j)
            acc[j] += qv * wk[d][es * 8 + j];
    }
    // direct fragment-order store (old k_split_u2 math, u round-trip removed)
    int m   = b * 8 + h;
    int e0s = e0 + es * 8;
    int ks  = e0s >> 5, quad = (e0s & 31) >> 3;
    int lane = (m & 15) + 16 * quad;
    int mt  = m >> 4;
    size_t base = ((((size_t)c * 16 + mt) * 16 + ks) * 512) + (size_t)lane * 8;
    s8_t vh, vm;
    #pragma unroll
    for (int j = 0; j < 8; ++j) {
        float xv = acc[j] * 32.0f, fh, fm;
        vh[j] = (short)f16_round(xv, fh);
        vm[j] = (short)f16_round(xv - fh, fm);
    }
    *(s8_t*)(u2 + base)       = vh;
    *(s8_t*)(u2 + U2P + base) = vm;
    if (et == 0 && es == 0) {
        float s = 0.f;
        const float* bkr = bk + c * E_ + h * 64;
        for (int d = 0; d < 64; ++d) s += qs[b][d] * bkr[d];
        qb[c * 256 + b * 8 + h] = s;
    }
}

// ---------------------------------------------------------------------------
// Split A*32 into 2 fp16 planes, tiled per (nchunk 128, kstep 32) with the
// R5 within-row 16B-chunk swizzle -> zero LDS conflicts for B-frag reads.
// ---------------------------------------------------------------------------
__global__ void k_split_A2(const float* __restrict__ A, short* __restrict__ A2t) {
    int nc = blockIdx.x, ks = blockIdx.y;
    int tid = threadIdx.x;
    int n = tid >> 1, kg = (tid & 1) * 2;   // logical chunks kg, kg+1 of 4
    int gn = nc * 128 + n;
    const float* ap = A + (size_t)gn * 512 + ks * 32 + kg * 8;
    s8_t vh[2], vm[2];
    #pragma unroll
    for (int g = 0; g < 2; ++g)
        #pragma unroll
        for (int j = 0; j < 8; ++j) {
            float x = (gn < N_) ? ap[g * 8 + j] * 32.0f : 0.f;
            float fh, fm;
            vh[g][j] = (short)f16_round(x, fh);
            vm[g][j] = (short)f16_round(x - fh, fm);
        }
    short* outp = A2t + ((size_t)nc * 16 + ks) * 8192 + n * 32;
    #pragma unroll
    for (int g = 0; g < 2; ++g) {
        int p = ((kg + g) + (n >> 1)) & 3;
        *(s8_t*)(outp + p * 8)        = vh[g];
        *(s8_t*)(outp + 4096 + p * 8) = vm[g];
    }
}

// ---------------------------------------------------------------------------
// Main: S(m,n) = member ? exp(SCALE*(dot/1024 + qb)) : 0, 3-product fp16x2
// (hh, hm, mh) via 16x16x32 f16 MFMA. Unchanged from R12 (123->118 us,
// MfmaUtil 51, 4-block occupancy bound). TLP is the proven lever here;
// schedule experiments were nulls (R9/R10).
// ---------------------------------------------------------------------------
__global__ __launch_bounds__(256, 4) void k_scores_mfma(
        const short* __restrict__ u2, const short* __restrict__ A2t,
        const float* __restrict__ qb, const int* __restrict__ mask,
        float* __restrict__ S, float* __restrict__ Zpart, int c0, int CB) {
    __shared__ __align__(16) short As[16384];   // one 32 KB ks2-tile (2 kh)
    __shared__ float sQb[128];
    __shared__ int   sMask[128];
    int bx = blockIdx.x;
    int x     = bx & 7;
    int rest  = bx >> 3;
    int mh    = rest & 1;          // m-half: rows [mh*128, mh*128+128)
    int rest2 = rest >> 1;
    int z     = rest2 % CB;
    int g     = rest2 / CB;
    int nc    = g * 8 + x;
    if (nc >= NC3) return;
    int c  = c0 + z;
    int tid = threadIdx.x;
    int lane = tid & 63, w = tid >> 6;
    int quad = lane >> 4, l15 = lane & 15;
    int n0 = nc * 128;

    if (tid < 128) {
        sQb[tid] = qb[c * 256 + mh * 128 + tid];
        int n = n0 + tid;
        sMask[tid] = (n < N_) ? mask[(size_t)n * C_ + c] : 0;
    }

    f32x4 acc[2][8];   // [mt][nt] — wave owns 32 rows x 128 cols
    #pragma unroll
    for (int i = 0; i < 2; ++i)
        #pragma unroll
        for (int j = 0; j < 8; ++j)
            acc[i][j] = (f32x4){0.f, 0.f, 0.f, 0.f};

    const char* tb = (const char*)A2t + (size_t)nc * 262144;

    for (int ks2 = 0; ks2 < 8; ++ks2) {
        __syncthreads();   // all waves done reading As (and covers sQb/sMask)
        // async DMA this ks2's 32 KB (two 16 KB kh tiles): 32 segs of 1024 B
        const char* src = tb + (size_t)ks2 * 32768;
        #pragma unroll
        for (int t = 0; t < 8; ++t) {
            int seg = w * 8 + t;
            GLOAD_LDS16(src + (size_t)seg * 1024 + lane * 16,
                        (char*)As + seg * 1024);
        }
        __syncthreads();   // compiler drains vmcnt(0) before barrier

        #pragma unroll
        for (int kh = 0; kh < 2; ++kh) {
            int ks = ks2 * 2 + kh;
            const short* Ab = As + kh * 8192;
            // A-fragments (u2): 4 global 16B loads, L2/LLC-resident
            h8_t af[2][2];
            #pragma unroll
            for (int mt = 0; mt < 2; ++mt) {
                int mtg = mh * 8 + w * 2 + mt;
                size_t ub = ((((size_t)c * 16 + mtg) * 16 + ks) * 512)
                            + (size_t)lane * 8;
                af[mt][0] = *(const h8_t*)(u2 + ub);
                af[mt][1] = *(const h8_t*)(u2 + U2P + ub);
            }
            // two nt-halves; sched_barrier caps b-frag hoisting (reg budget)
            #pragma unroll
            for (int half = 0; half < 2; ++half) {
                __builtin_amdgcn_sched_barrier(0);
                #pragma unroll
                for (int q4 = 0; q4 < 4; ++q4) {
                    int nt = half * 4 + q4;
                    int r = nt * 16 + l15;
                    const short* bp = Ab + r * 32 + ((quad + (r >> 1)) & 3) * 8;
                    h8_t b0 = *(const h8_t*)bp;
                    h8_t b1 = *(const h8_t*)(bp + 4096);
                    #pragma unroll
                    for (int mt = 0; mt < 2; ++mt) {
                        f32x4 a = acc[mt][nt];
                        a = MFMAH(af[mt][0], b0, a);   // hh
                        a = MFMAH(af[mt][0], b1, a);   // hm
                        a = MFMAH(af[mt][1], b0, a);   // mh
                        acc[mt][nt] = a;
                    }
                }
            }
        }
    }

    // Epilogue: unscale + bias + mask + exp, write S, fused deterministic
    // row-sums.  C/D: col = lane&15, row = quad*4 + r (m89/m91).
    float* Sc = S + (size_t)z * SSZ;
    #pragma unroll
    for (int mt = 0; mt < 2; ++mt) {
        float rs[4] = {0.f, 0.f, 0.f, 0.f};
        #pragma unroll
        for (int nt = 0; nt < 8; ++nt) {
            int nl = nt * 16 + l15;
            int n = n0 + nl;
            int mem = sMask[nl];
            #pragma unroll
            for (int r = 0; r < 4; ++r) {
                int ml = w * 32 + mt * 16 + quad * 4 + r;   // local row in half
                float sc = SCALE * (acc[mt][nt][r] * UNSC + sQb[ml]);
                float ev = mem ? __expf(sc) : 0.f;
                rs[r] += ev;
                if (n < N_) Sc[(size_t)(mh * 128 + ml) * N_ + n] = ev;
            }
        }
        #pragma unroll
        for (int r = 0; r < 4; ++r) {
            float v = rs[r];
            v += __shfl_xor(v, 1); v += __shfl_xor(v, 2);
            v += __shfl_xor(v, 4); v += __shfl_xor(v, 8);
            if (l15 == 0) {
                int ml = w * 32 + mt * 16 + quad * 4 + r;
                Zpart[((size_t)nc * C_ + c) * 256 + mh * 128 + ml] = v;
            }
        }
    }
}

// ---------------------------------------------------------------------------
// Z(c,m) = sum_nc Zpart(nc,c,m). grid = CB blocks x 256 thr.
// ---------------------------------------------------------------------------
__global__ void k_zsum(const float* __restrict__ Zpart, float* __restrict__ Z, int c0) {
    int c = c0 + blockIdx.x;
    int i = c * 256 + threadIdx.x;
    float s = 0.f;
    for (int nc = 0; nc < NC3; ++nc) s += Zpart[(size_t)nc * (C_ * 256) + i];
    Z[i] = s;
}

// ---------------------------------------------------------------------------
// K3 (R13): wave-autonomous fused head-average + chunk top-ns.
// Each WAVE owns one 1024-chunk: 16 values/lane in registers (4 float4
// groups of 256, perfectly coalesced), 5 rounds of {16-slot local scan ->
// 64-lane butterfly -> in-register removal}. Zero __syncthreads, zero LDS,
// no serial merge (R12's serial thread-0 merge was the suspected +26 us
// regression). Tie-break: value desc, index asc — identical to jax top_k.
// grid (NCH/4, B, CB), block 256 = 4 independent waves.
// ---------------------------------------------------------------------------
__global__ __launch_bounds__(256) void k_topk1(
        const float* __restrict__ S, const float* __restrict__ Z,
        float2* __restrict__ cand, int c0, int ns) {
    int b = blockIdx.y, z = blockIdx.z;
    int tid = threadIdx.x;
    int lane = tid & 63, w = tid >> 6;
    int chunk = blockIdx.x * 4 + w;
    const float* Sc = S + (size_t)z * SSZ;

    float zr[H_];
    #pragma unroll
    for (int h = 0; h < H_; ++h)
        zr[h] = 0.125f / Z[(c0 + z) * (B_ * H_) + b * H_ + h];

    int base = chunk * CHUNK + lane * 4;   // slot s=j*4+t -> n = base+j*256+t
    float va[16];
    #pragma unroll
    for (int s = 0; s < 16; ++s) va[s] = 0.f;
    bool ok[4];
    #pragma unroll
    for (int j = 0; j < 4; ++j) ok[j] = (base + j * 256) < N_;  // N_%4==0

    #pragma unroll
    for (int h = 0; h < H_; ++h) {
        const float* row = Sc + (size_t)(b * H_ + h) * N_;
        float wz = zr[h];
        #pragma unroll
        for (int j = 0; j < 4; ++j) {
            if (ok[j]) {
                const float4 sv = *(const float4*)&row[base + j * 256];
                va[j * 4 + 0] += sv.x * wz;
                va[j * 4 + 1] += sv.y * wz;
                va[j * 4 + 2] += sv.z * wz;
                va[j * 4 + 3] += sv.w * wz;
            }
        }
    }
    #pragma unroll
    for (int j = 0; j < 4; ++j)
        if (!ok[j]) {
            va[j * 4 + 0] = -1.f; va[j * 4 + 1] = -1.f;
            va[j * 4 + 2] = -1.f; va[j * 4 + 3] = -1.f;
        }

    float2* cp = cand + (((size_t)z * B_ + b) * NCH + chunk) * ns;
    for (int j = 0; j < ns; ++j) {
        // local max over 16 slots; ascending scan + strict > keeps lowest n
        float bv = va[0]; int bs = 0;
        #pragma unroll
        for (int s = 1; s < 16; ++s)
            if (va[s] > bv) { bv = va[s]; bs = s; }
        int bn = ok[bs >> 2] ? (base + ((bs >> 2) << 8) + (bs & 3)) : N_;
        // 64-lane butterfly (all lanes converge on wave winner)
        #pragma unroll
        for (int off = 1; off < 64; off <<= 1) {
            float ov = __shfl_xor(bv, off, 64);
            int   on = __shfl_xor(bn, off, 64);
            if (ov > bv || (ov == bv && on < bn)) { bv = ov; bn = on; }
        }
        if (lane == 0) cp[j] = make_float2(bv, (float)bn);
        // in-register removal: only the owner lane matches bn
        #pragma unroll
        for (int s = 0; s < 16; ++s) {
            int n_s = base + ((s >> 2) << 8) + (s & 3);
            if (n_s == bn) va[s] = -2.f;
        }
    }
}

// ---------------------------------------------------------------------------
// K4: merge NCH*ns candidates -> final top-ns per (b, class). grid (B, CB).
// ---------------------------------------------------------------------------
__global__ __launch_bounds__(256) void k_topk2(
        const float2* __restrict__ cand, float* __restrict__ out, int c0, int ns) {
    int b = blockIdx.x, z = blockIdx.y;
    int c = c0 + z;
    int tid = threadIdx.x;
    int ncand = NCH * ns;   // 100
    const float2* cb = cand + ((size_t)z * B_ + b) * ncand;
    float v = -3.f; int ix = N_ + 1;
    if (tid < ncand) { float2 e = cb[tid]; v = e.x; ix = (int)e.y; }
    __shared__ float sv[256];
    __shared__ int   si[256];
    __shared__ int   win;
    for (int j = 0; j < ns; ++j) {
        sv[tid] = v; si[tid] = ix;
        __syncthreads();
        for (int w = 128; w >= 1; w >>= 1) {
            if (tid < w) {
                float v2 = sv[tid + w]; int i2 = si[tid + w];
                if (v2 > sv[tid] || (v2 == sv[tid] && i2 < si[tid])) {
                    sv[tid] = v2; si[tid] = i2;
                }
            }
            __syncthreads();
        }
        if (tid == 0) {
            out[((size_t)b * C_ + c) * ns + j] = (float)si[0];
            out[(size_t)B_ * C_ * ns + ((size_t)b * C_ + c) * ns + j] = sv[0];
            win = si[0];
        }
        __syncthreads();
        if (ix == win) v = -3.f;
        __syncthreads();
    }
}

// ---------------------------------------------------------------------------
extern "C" void kernel_launch(void* const* d_in, const int* in_sizes, int n_in,
                              void* d_out, int out_size, void* d_ws, size_t ws_size,
                              hipStream_t stream) {
    const float* x    = (const float*)d_in[0];  // (B,E)
    const float* A    = (const float*)d_in[1];  // (N,E)
    const int*   mask = (const int*)  d_in[2];  // (N,C)
    const float* Wq   = (const float*)d_in[3];  // (C,E,E)
    const float* bq   = (const float*)d_in[4];  // (C,E)
    const float* Wk   = (const float*)d_in[5];  // (C,E,E)
    const float* bk   = (const float*)d_in[6];  // (C,E)
    float* out = (float*)d_out;

    int ns = out_size / (2 * B_ * C_);          // = n_samples (5)

    // Workspace carve (floats) — u buffer removed (k_u2 writes u2 directly)
    float* ws = (float*)d_ws;
    float* q     = ws;                                    // 131072
    float* qb    = q     + (size_t)C_ * B_ * E_;          // 2048
    float* Z     = qb    + (size_t)C_ * B_ * H_;          // 2048
    float* Zpart = Z     + (size_t)C_ * B_ * H_;          // NC3*8*256 = 321536
    short* u2    = (short*)(Zpart + (size_t)NC3 * C_ * 256);   // 2*1048576 shorts
    short* A2t   = u2 + 2 * U2P;                               // NC3*16*8192 shorts
    float* S     = (float*)(A2t + (size_t)NC3 * 16 * 8192);
    size_t fixedFloats = (size_t)(S - ws);

    size_t candFloats = (size_t)C_ * B_ * NCH * ns * 2;
    int CB = 8;
    while (CB > 1 &&
           (fixedFloats + (size_t)CB * SSZ + candFloats + 16) * 4 > ws_size)
        CB >>= 1;
    float2* cand = (float2*)(S + (size_t)CB * SSZ);

    k_q2<<<dim3(64, C_), 256, 0, stream>>>(x, Wq, bq, q);
    k_u2<<<dim3(8, H_, C_), 256, 0, stream>>>(q, Wk, bk, u2, qb);
    k_split_A2<<<dim3(NC3, 16), 256, 0, stream>>>(A, A2t);

    for (int c0 = 0; c0 < C_; c0 += CB) {
        // grid: (g, z, mh, x) packed; 2 m-half blocks per (nc, c)
        k_scores_mfma<<<NCG * 2 * 8 * CB, 256, 0, stream>>>(u2, A2t, qb, mask, S, Zpart, c0, CB);
        k_zsum<<<CB, 256, 0, stream>>>(Zpart, Z, c0);
        k_topk1<<<dim3(NCH / 4, B_, CB), 256, 0, stream>>>(S, Z, cand, c0, ns);
        k_topk2<<<dim3(B_, CB), 256, 0, stream>>>(cand, out, c0, ns);
    }
}

// Round 6
// 352.961 us; speedup vs baseline: 1.1172x; 1.0358x over previous
//
#include <hip/hip_runtime.h>
#include <math.h>

// Problem constants (fixed by setup_inputs)
#define B_  32
#define N_  20000
#define C_  8
#define E_  512
#define H_  8
#define SCALE 0.125f    // 1/sqrt(64)
#define UNSC  9.765625e-4f   // 1/1024 = 1/(32*32) operand pre-scale undo

#define CHUNK 1024
#define NCH   20       // ceil(20000/1024) (top-k chunking)
#define NC3   157      // ceil(20000/128)  (GEMM n-chunks, BN=128)
#define NCG   20       // ceil(NC3/8) nc-groups for XCD swizzle
#define SSZ ((size_t)B_ * H_ * N_)   // per-class S floats (256*20000)

typedef __attribute__((ext_vector_type(8))) _Float16 h8_t;  // 8 fp16 (4 VGPRs)
typedef __attribute__((ext_vector_type(8))) short   s8_t;   // 8 shorts (16 B)
typedef __attribute__((ext_vector_type(4))) float f32x4;    // 16x16 MFMA acc

#define MFMAH(a, b, c) __builtin_amdgcn_mfma_f32_16x16x32_f16(a, b, c, 0, 0, 0)

// async global->LDS, 16B per lane, wave-uniform LDS base + lane*16
#define GLOAD_LDS16(g, l)                                              \
    __builtin_amdgcn_global_load_lds(                                  \
        (const __attribute__((address_space(1))) unsigned int*)(g),    \
        (__attribute__((address_space(3))) unsigned int*)(l), 16, 0, 0)

// RNE round-to-fp16, returns bit pattern + rounded value
__device__ inline unsigned short f16_round(float x, float& fv) {
    _Float16 h = (_Float16)x;
    fv = (float)h;
    union { _Float16 hh; unsigned short us; } u;
    u.hh = h;
    return u.us;
}

#define U2P ((size_t)C_ * 16 * 16 * 512)   // 1,048,576 shorts per plane

// ---------------------------------------------------------------------------
// K_prep (R14): fused [k_split_A2 || k_q2] — independent works, one launch.
// blocks [0, NC3*16): A-split (nc = bid>>4, ks = bid&15), R5 swizzle layout.
// blocks [NC3*16, NC3*16+512): q2 (ft = r&63, c = r>>6).
// ---------------------------------------------------------------------------
__global__ __launch_bounds__(256) void k_prep(
        const float* __restrict__ A, short* __restrict__ A2t,
        const float* __restrict__ x, const float* __restrict__ Wq,
        const float* __restrict__ bq, float* __restrict__ q) {
    int bid = blockIdx.x;
    int tid = threadIdx.x;
    if (bid < NC3 * 16) {
        // ---- A-split: 2 fp16 planes, (nchunk 128, kstep 32) tiles ----
        int nc = bid >> 4, ks = bid & 15;
        int n = tid >> 1, kg = (tid & 1) * 2;   // logical chunks kg, kg+1 of 4
        int gn = nc * 128 + n;
        const float* ap = A + (size_t)gn * 512 + ks * 32 + kg * 8;
        s8_t vh[2], vm[2];
        #pragma unroll
        for (int g = 0; g < 2; ++g)
            #pragma unroll
            for (int j = 0; j < 8; ++j) {
                float xv = (gn < N_) ? ap[g * 8 + j] * 32.0f : 0.f;
                float fh, fm;
                vh[g][j] = (short)f16_round(xv, fh);
                vm[g][j] = (short)f16_round(xv - fh, fm);
            }
        short* outp = A2t + ((size_t)nc * 16 + ks) * 8192 + n * 32;
        #pragma unroll
        for (int g = 0; g < 2; ++g) {
            int p = ((kg + g) + (n >> 1)) & 3;
            *(s8_t*)(outp + p * 8)        = vh[g];
            *(s8_t*)(outp + 4096 + p * 8) = vm[g];
        }
    } else {
        // ---- q2: q(c,b,f) = sum_e x(b,e) * Wq[c][f,e] + bq[c][f] ----
        int r = bid - NC3 * 16;
        int ft = r & 63, c = r >> 6;
        int f0 = ft * 8;
        __shared__ float wsm[8][66];
        __shared__ float xs[32][66];
        int b = tid & 31, fs = tid >> 5;
        float acc = 0.f;
        const float* W = Wq + (size_t)c * E_ * E_;
        for (int k0 = 0; k0 < E_; k0 += 64) {
            __syncthreads();
            for (int i = tid; i < 512; i += 256)
                wsm[i >> 6][i & 63] = W[(size_t)(f0 + (i >> 6)) * E_ + k0 + (i & 63)];
            for (int i = tid; i < 2048; i += 256)
                xs[i >> 6][i & 63] = x[(size_t)(i >> 6) * E_ + k0 + (i & 63)];
            __syncthreads();
            #pragma unroll
            for (int kk = 0; kk < 64; ++kk)
                acc += xs[b][kk] * wsm[fs][kk];
        }
        q[((size_t)c * B_ + b) * E_ + f0 + fs] = acc + bq[c * E_ + f0 + fs];
    }
}

// ---------------------------------------------------------------------------
// K1b (fused with u2-split): u(c, m=(b*8+h), e) = sum_d q(c,b,h*64+d) *
// Wk[c][h*64+d, e], written DIRECTLY as 2 fp16 planes in 16x16x32 A-fragment
// order. Eliminates the u round-trip (8 MB) and a kernel launch.
// ---------------------------------------------------------------------------
__global__ __launch_bounds__(256) void k_u2(
        const float* __restrict__ q, const float* __restrict__ Wk,
        const float* __restrict__ bk, short* __restrict__ u2,
        float* __restrict__ qb) {
    int et = blockIdx.x, h = blockIdx.y, c = blockIdx.z;
    int e0 = et * 64;
    __shared__ float qs[32][66];
    __shared__ float wk[64][66];
    int tid = threadIdx.x;
    int b = tid & 31, es = tid >> 5;
    for (int i = tid; i < 2048; i += 256)
        qs[i >> 6][i & 63] = q[((size_t)c * B_ + (i >> 6)) * E_ + h * 64 + (i & 63)];
    const float* W = Wk + (size_t)c * E_ * E_ + (size_t)(h * 64) * E_;
    for (int i = tid; i < 4096; i += 256)
        wk[i >> 6][i & 63] = W[(size_t)(i >> 6) * E_ + e0 + (i & 63)];
    __syncthreads();
    float acc[8] = {};
    for (int d = 0; d < 64; ++d) {
        float qv = qs[b][d];
        #pragma unroll
        for (int j = 0; j < 8; ++j)
            acc[j] += qv * wk[d][es * 8 + j];
    }
    // direct fragment-order store (old k_split_u2 math, u round-trip removed)
    int m   = b * 8 + h;
    int e0s = e0 + es * 8;
    int ks  = e0s >> 5, quad = (e0s & 31) >> 3;
    int lane = (m & 15) + 16 * quad;
    int mt  = m >> 4;
    size_t base = ((((size_t)c * 16 + mt) * 16 + ks) * 512) + (size_t)lane * 8;
    s8_t vh, vm;
    #pragma unroll
    for (int j = 0; j < 8; ++j) {
        float xv = acc[j] * 32.0f, fh, fm;
        vh[j] = (short)f16_round(xv, fh);
        vm[j] = (short)f16_round(xv - fh, fm);
    }
    *(s8_t*)(u2 + base)       = vh;
    *(s8_t*)(u2 + U2P + base) = vm;
    if (et == 0 && es == 0) {
        float s = 0.f;
        const float* bkr = bk + c * E_ + h * 64;
        for (int d = 0; d < 64; ++d) s += qs[b][d] * bkr[d];
        qb[c * 256 + b * 8 + h] = s;
    }
}

// ---------------------------------------------------------------------------
// Main: S(m,n) = member ? exp(SCALE*(dot/1024 + qb)) : 0, 3-product fp16x2
// (hh, hm, mh) via 16x16x32 f16 MFMA. Unchanged from R12/R13 (119 us,
// MfmaUtil 50, occupancy bound (256,4)). TLP is the proven lever here;
// schedule experiments were nulls (R9/R10).
// ---------------------------------------------------------------------------
__global__ __launch_bounds__(256, 4) void k_scores_mfma(
        const short* __restrict__ u2, const short* __restrict__ A2t,
        const float* __restrict__ qb, const int* __restrict__ mask,
        float* __restrict__ S, float* __restrict__ Zpart, int c0, int CB) {
    __shared__ __align__(16) short As[16384];   // one 32 KB ks2-tile (2 kh)
    __shared__ float sQb[128];
    __shared__ int   sMask[128];
    int bx = blockIdx.x;
    int x     = bx & 7;
    int rest  = bx >> 3;
    int mh    = rest & 1;          // m-half: rows [mh*128, mh*128+128)
    int rest2 = rest >> 1;
    int z     = rest2 % CB;
    int g     = rest2 / CB;
    int nc    = g * 8 + x;
    if (nc >= NC3) return;
    int c  = c0 + z;
    int tid = threadIdx.x;
    int lane = tid & 63, w = tid >> 6;
    int quad = lane >> 4, l15 = lane & 15;
    int n0 = nc * 128;

    if (tid < 128) {
        sQb[tid] = qb[c * 256 + mh * 128 + tid];
        int n = n0 + tid;
        sMask[tid] = (n < N_) ? mask[(size_t)n * C_ + c] : 0;
    }

    f32x4 acc[2][8];   // [mt][nt] — wave owns 32 rows x 128 cols
    #pragma unroll
    for (int i = 0; i < 2; ++i)
        #pragma unroll
        for (int j = 0; j < 8; ++j)
            acc[i][j] = (f32x4){0.f, 0.f, 0.f, 0.f};

    const char* tb = (const char*)A2t + (size_t)nc * 262144;

    for (int ks2 = 0; ks2 < 8; ++ks2) {
        __syncthreads();   // all waves done reading As (and covers sQb/sMask)
        // async DMA this ks2's 32 KB (two 16 KB kh tiles): 32 segs of 1024 B
        const char* src = tb + (size_t)ks2 * 32768;
        #pragma unroll
        for (int t = 0; t < 8; ++t) {
            int seg = w * 8 + t;
            GLOAD_LDS16(src + (size_t)seg * 1024 + lane * 16,
                        (char*)As + seg * 1024);
        }
        __syncthreads();   // compiler drains vmcnt(0) before barrier

        #pragma unroll
        for (int kh = 0; kh < 2; ++kh) {
            int ks = ks2 * 2 + kh;
            const short* Ab = As + kh * 8192;
            // A-fragments (u2): 4 global 16B loads, L2/LLC-resident
            h8_t af[2][2];
            #pragma unroll
            for (int mt = 0; mt < 2; ++mt) {
                int mtg = mh * 8 + w * 2 + mt;
                size_t ub = ((((size_t)c * 16 + mtg) * 16 + ks) * 512)
                            + (size_t)lane * 8;
                af[mt][0] = *(const h8_t*)(u2 + ub);
                af[mt][1] = *(const h8_t*)(u2 + U2P + ub);
            }
            // two nt-halves; sched_barrier caps b-frag hoisting (reg budget)
            #pragma unroll
            for (int half = 0; half < 2; ++half) {
                __builtin_amdgcn_sched_barrier(0);
                #pragma unroll
                for (int q4 = 0; q4 < 4; ++q4) {
                    int nt = half * 4 + q4;
                    int r = nt * 16 + l15;
                    const short* bp = Ab + r * 32 + ((quad + (r >> 1)) & 3) * 8;
                    h8_t b0 = *(const h8_t*)bp;
                    h8_t b1 = *(const h8_t*)(bp + 4096);
                    #pragma unroll
                    for (int mt = 0; mt < 2; ++mt) {
                        f32x4 a = acc[mt][nt];
                        a = MFMAH(af[mt][0], b0, a);   // hh
                        a = MFMAH(af[mt][0], b1, a);   // hm
                        a = MFMAH(af[mt][1], b0, a);   // mh
                        acc[mt][nt] = a;
                    }
                }
            }
        }
    }

    // Epilogue: unscale + bias + mask + exp, write S, fused deterministic
    // row-sums.  C/D: col = lane&15, row = quad*4 + r (m89/m91).
    float* Sc = S + (size_t)z * SSZ;
    #pragma unroll
    for (int mt = 0; mt < 2; ++mt) {
        float rs[4] = {0.f, 0.f, 0.f, 0.f};
        #pragma unroll
        for (int nt = 0; nt < 8; ++nt) {
            int nl = nt * 16 + l15;
            int n = n0 + nl;
            int mem = sMask[nl];
            #pragma unroll
            for (int r = 0; r < 4; ++r) {
                int ml = w * 32 + mt * 16 + quad * 4 + r;   // local row in half
                float sc = SCALE * (acc[mt][nt][r] * UNSC + sQb[ml]);
                float ev = mem ? __expf(sc) : 0.f;
                rs[r] += ev;
                if (n < N_) Sc[(size_t)(mh * 128 + ml) * N_ + n] = ev;
            }
        }
        #pragma unroll
        for (int r = 0; r < 4; ++r) {
            float v = rs[r];
            v += __shfl_xor(v, 1); v += __shfl_xor(v, 2);
            v += __shfl_xor(v, 4); v += __shfl_xor(v, 8);
            if (l15 == 0) {
                int ml = w * 32 + mt * 16 + quad * 4 + r;
                Zpart[((size_t)nc * C_ + c) * 256 + mh * 128 + ml] = v;
            }
        }
    }
}

// ---------------------------------------------------------------------------
// K3 (R14): wave-autonomous fused [zsum + head-average + chunk top-ns].
// Each WAVE owns one 1024-chunk. Inline Z: lanes 0-7 sum Zpart over nc in
// the SAME sequential order as the old k_zsum (bitwise-identical Z), then
// 8 shfl broadcasts. Then 16 values/lane in registers, 5 rounds of
// {16-slot local scan -> 64-lane butterfly -> in-register removal}.
// Zero __syncthreads, zero LDS. grid (NCH/4, B, CB), block 256 = 4 waves.
// ---------------------------------------------------------------------------
__global__ __launch_bounds__(256) void k_topk1(
        const float* __restrict__ S, const float* __restrict__ Zpart,
        float2* __restrict__ cand, int c0, int ns) {
    int b = blockIdx.y, z = blockIdx.z;
    int tid = threadIdx.x;
    int lane = tid & 63, w = tid >> 6;
    int chunk = blockIdx.x * 4 + w;
    int c = c0 + z;
    const float* Sc = S + (size_t)z * SSZ;

    // inline Z (replaces k_zsum): sequential over nc — order-preserving
    float zrl = 0.f;
    if (lane < H_) {
        float s = 0.f;
        const float* zp = Zpart + (size_t)c * 256 + b * 8 + lane;
        for (int nc = 0; nc < NC3; ++nc) s += zp[(size_t)nc * (C_ * 256)];
        zrl = 0.125f / s;
    }
    float zr[H_];
    #pragma unroll
    for (int h = 0; h < H_; ++h) zr[h] = __shfl(zrl, h, 64);

    int base = chunk * CHUNK + lane * 4;   // slot s=j*4+t -> n = base+j*256+t
    float va[16];
    #pragma unroll
    for (int s = 0; s < 16; ++s) va[s] = 0.f;
    bool ok[4];
    #pragma unroll
    for (int j = 0; j < 4; ++j) ok[j] = (base + j * 256) < N_;  // N_%4==0

    #pragma unroll
    for (int h = 0; h < H_; ++h) {
        const float* row = Sc + (size_t)(b * H_ + h) * N_;
        float wz = zr[h];
        #pragma unroll
        for (int j = 0; j < 4; ++j) {
            if (ok[j]) {
                const float4 sv = *(const float4*)&row[base + j * 256];
                va[j * 4 + 0] += sv.x * wz;
                va[j * 4 + 1] += sv.y * wz;
                va[j * 4 + 2] += sv.z * wz;
                va[j * 4 + 3] += sv.w * wz;
            }
        }
    }
    #pragma unroll
    for (int j = 0; j < 4; ++j)
        if (!ok[j]) {
            va[j * 4 + 0] = -1.f; va[j * 4 + 1] = -1.f;
            va[j * 4 + 2] = -1.f; va[j * 4 + 3] = -1.f;
        }

    float2* cp = cand + (((size_t)z * B_ + b) * NCH + chunk) * ns;
    for (int j = 0; j < ns; ++j) {
        // local max over 16 slots; ascending scan + strict > keeps lowest n
        float bv = va[0]; int bs = 0;
        #pragma unroll
        for (int s = 1; s < 16; ++s)
            if (va[s] > bv) { bv = va[s]; bs = s; }
        int bn = ok[bs >> 2] ? (base + ((bs >> 2) << 8) + (bs & 3)) : N_;
        // 64-lane butterfly (all lanes converge on wave winner)
        #pragma unroll
        for (int off = 1; off < 64; off <<= 1) {
            float ov = __shfl_xor(bv, off, 64);
            int   on = __shfl_xor(bn, off, 64);
            if (ov > bv || (ov == bv && on < bn)) { bv = ov; bn = on; }
        }
        if (lane == 0) cp[j] = make_float2(bv, (float)bn);
        // in-register removal: only the owner lane matches bn
        #pragma unroll
        for (int s = 0; s < 16; ++s) {
            int n_s = base + ((s >> 2) << 8) + (s & 3);
            if (n_s == bn) va[s] = -2.f;
        }
    }
}

// ---------------------------------------------------------------------------
// K4 (R14): single-wave barrier-free merge of NCH*ns=100 candidates ->
// final top-ns per (b, class). Lane holds cands {l, l+64}; 5 rounds of
// {pair max -> butterfly -> removal}. Identical tie-break (value desc,
// index asc). grid (B, CB), block 64.
// ---------------------------------------------------------------------------
__global__ __launch_bounds__(64) void k_topk2(
        const float2* __restrict__ cand, float* __restrict__ out, int c0, int ns) {
    int b = blockIdx.x, z = blockIdx.y;
    int c = c0 + z;
    int lane = threadIdx.x;
    int ncand = NCH * ns;   // 100
    const float2* cb = cand + ((size_t)z * B_ + b) * ncand;
    float v0 = -3.f, v1 = -3.f;
    int   i0 = N_ + 1, i1 = N_ + 2;
    if (lane < ncand)      { float2 e = cb[lane];      v0 = e.x; i0 = (int)e.y; }
    if (lane + 64 < ncand) { float2 e = cb[lane + 64]; v1 = e.x; i1 = (int)e.y; }
    for (int j = 0; j < ns; ++j) {
        float bv = v0; int bn = i0;
        if (v1 > bv || (v1 == bv && i1 < bn)) { bv = v1; bn = i1; }
        #pragma unroll
        for (int off = 1; off < 64; off <<= 1) {
            float ov = __shfl_xor(bv, off, 64);
            int   on = __shfl_xor(bn, off, 64);
            if (ov > bv || (ov == bv && on < bn)) { bv = ov; bn = on; }
        }
        if (lane == 0) {
            out[((size_t)b * C_ + c) * ns + j] = (float)bn;
            out[(size_t)B_ * C_ * ns + ((size_t)b * C_ + c) * ns + j] = bv;
        }
        if (i0 == bn) v0 = -3.f;
        if (i1 == bn) v1 = -3.f;
    }
}

// ---------------------------------------------------------------------------
extern "C" void kernel_launch(void* const* d_in, const int* in_sizes, int n_in,
                              void* d_out, int out_size, void* d_ws, size_t ws_size,
                              hipStream_t stream) {
    const float* x    = (const float*)d_in[0];  // (B,E)
    const float* A    = (const float*)d_in[1];  // (N,E)
    const int*   mask = (const int*)  d_in[2];  // (N,C)
    const float* Wq   = (const float*)d_in[3];  // (C,E,E)
    const float* bq   = (const float*)d_in[4];  // (C,E)
    const float* Wk   = (const float*)d_in[5];  // (C,E,E)
    const float* bk   = (const float*)d_in[6];  // (C,E)
    float* out = (float*)d_out;

    int ns = out_size / (2 * B_ * C_);          // = n_samples (5)

    // Workspace carve (floats) — u and Z buffers removed
    float* ws = (float*)d_ws;
    float* q     = ws;                                    // 131072
    float* qb    = q     + (size_t)C_ * B_ * E_;          // 2048
    float* Zpart = qb    + (size_t)C_ * B_ * H_;          // NC3*8*256 = 321536
    short* u2    = (short*)(Zpart + (size_t)NC3 * C_ * 256);   // 2*1048576 shorts
    short* A2t   = u2 + 2 * U2P;                               // NC3*16*8192 shorts
    float* S     = (float*)(A2t + (size_t)NC3 * 16 * 8192);
    size_t fixedFloats = (size_t)(S - ws);

    size_t candFloats = (size_t)C_ * B_ * NCH * ns * 2;
    int CB = 8;
    while (CB > 1 &&
           (fixedFloats + (size_t)CB * SSZ + candFloats + 16) * 4 > ws_size)
        CB >>= 1;
    float2* cand = (float2*)(S + (size_t)CB * SSZ);

    k_prep<<<NC3 * 16 + 512, 256, 0, stream>>>(A, A2t, x, Wq, bq, q);
    k_u2<<<dim3(8, H_, C_), 256, 0, stream>>>(q, Wk, bk, u2, qb);

    for (int c0 = 0; c0 < C_; c0 += CB) {
        // grid: (g, z, mh, x) packed; 2 m-half blocks per (nc, c)
        k_scores_mfma<<<NCG * 2 * 8 * CB, 256, 0, stream>>>(u2, A2t, qb, mask, S, Zpart, c0, CB);
        k_topk1<<<dim3(NCH / 4, B_, CB), 256, 0, stream>>>(S, Zpart, cand, c0, ns);
        k_topk2<<<dim3(B_, CB), 64, 0, stream>>>(cand, out, c0, ns);
    }
}

// Round 7
// 324.721 us; speedup vs baseline: 1.2144x; 1.0870x over previous
//
#include <hip/hip_runtime.h>
#include <math.h>

// Problem constants (fixed by setup_inputs)
#define B_  32
#define N_  20000
#define C_  8
#define E_  512
#define H_  8
#define SCALE 0.125f    // 1/sqrt(64)
#define UNSC  9.765625e-4f   // 1/1024 = 1/(32*32) operand pre-scale undo

#define CHUNK 1024
#define NCH   20       // ceil(20000/1024) (top-k chunking)
#define NC3   157      // ceil(20000/128)  (GEMM n-chunks, BN=128)
#define NCG   20       // ceil(NC3/8) nc-groups for XCD swizzle
#define SSZ ((size_t)B_ * H_ * N_)   // per-class S floats (256*20000)

typedef __attribute__((ext_vector_type(8))) _Float16 h8_t;  // 8 fp16 (4 VGPRs)
typedef __attribute__((ext_vector_type(8))) short   s8_t;   // 8 shorts (16 B)
typedef __attribute__((ext_vector_type(4))) float f32x4;    // 16x16 MFMA acc

#define MFMAH(a, b, c) __builtin_amdgcn_mfma_f32_16x16x32_f16(a, b, c, 0, 0, 0)

// async global->LDS, 16B per lane, wave-uniform LDS base + lane*16
#define GLOAD_LDS16(g, l)                                              \
    __builtin_amdgcn_global_load_lds(                                  \
        (const __attribute__((address_space(1))) unsigned int*)(g),    \
        (__attribute__((address_space(3))) unsigned int*)(l), 16, 0, 0)

// RNE round-to-fp16, returns bit pattern + rounded value
__device__ inline unsigned short f16_round(float x, float& fv) {
    _Float16 h = (_Float16)x;
    fv = (float)h;
    union { _Float16 hh; unsigned short us; } u;
    u.hh = h;
    return u.us;
}

#define U2P ((size_t)C_ * 16 * 16 * 512)   // 1,048,576 shorts per plane

// ---------------------------------------------------------------------------
// K_prep: fused [k_split_A2 || k_q2] — independent works, one launch.
// blocks [0, NC3*16): A-split (nc = bid>>4, ks = bid&15), R5 swizzle layout.
// blocks [NC3*16, NC3*16+512): q2 (ft = r&63, c = r>>6).
// ---------------------------------------------------------------------------
__global__ __launch_bounds__(256) void k_prep(
        const float* __restrict__ A, short* __restrict__ A2t,
        const float* __restrict__ x, const float* __restrict__ Wq,
        const float* __restrict__ bq, float* __restrict__ q) {
    int bid = blockIdx.x;
    int tid = threadIdx.x;
    if (bid < NC3 * 16) {
        // ---- A-split: 2 fp16 planes, (nchunk 128, kstep 32) tiles ----
        int nc = bid >> 4, ks = bid & 15;
        int n = tid >> 1, kg = (tid & 1) * 2;   // logical chunks kg, kg+1 of 4
        int gn = nc * 128 + n;
        const float* ap = A + (size_t)gn * 512 + ks * 32 + kg * 8;
        s8_t vh[2], vm[2];
        #pragma unroll
        for (int g = 0; g < 2; ++g)
            #pragma unroll
            for (int j = 0; j < 8; ++j) {
                float xv = (gn < N_) ? ap[g * 8 + j] * 32.0f : 0.f;
                float fh, fm;
                vh[g][j] = (short)f16_round(xv, fh);
                vm[g][j] = (short)f16_round(xv - fh, fm);
            }
        short* outp = A2t + ((size_t)nc * 16 + ks) * 8192 + n * 32;
        #pragma unroll
        for (int g = 0; g < 2; ++g) {
            int p = ((kg + g) + (n >> 1)) & 3;
            *(s8_t*)(outp + p * 8)        = vh[g];
            *(s8_t*)(outp + 4096 + p * 8) = vm[g];
        }
    } else {
        // ---- q2: q(c,b,f) = sum_e x(b,e) * Wq[c][f,e] + bq[c][f] ----
        int r = bid - NC3 * 16;
        int ft = r & 63, c = r >> 6;
        int f0 = ft * 8;
        __shared__ float wsm[8][66];
        __shared__ float xs[32][66];
        int b = tid & 31, fs = tid >> 5;
        float acc = 0.f;
        const float* W = Wq + (size_t)c * E_ * E_;
        for (int k0 = 0; k0 < E_; k0 += 64) {
            __syncthreads();
            for (int i = tid; i < 512; i += 256)
                wsm[i >> 6][i & 63] = W[(size_t)(f0 + (i >> 6)) * E_ + k0 + (i & 63)];
            for (int i = tid; i < 2048; i += 256)
                xs[i >> 6][i & 63] = x[(size_t)(i >> 6) * E_ + k0 + (i & 63)];
            __syncthreads();
            #pragma unroll
            for (int kk = 0; kk < 64; ++kk)
                acc += xs[b][kk] * wsm[fs][kk];
        }
        q[((size_t)c * B_ + b) * E_ + f0 + fs] = acc + bq[c * E_ + f0 + fs];
    }
}

// ---------------------------------------------------------------------------
// K1b (fused with u2-split): u(c, m=(b*8+h), e) = sum_d q(c,b,h*64+d) *
// Wk[c][h*64+d, e], written DIRECTLY as 2 fp16 planes in 16x16x32 A-fragment
// order. Eliminates the u round-trip (8 MB) and a kernel launch.
// ---------------------------------------------------------------------------
__global__ __launch_bounds__(256) void k_u2(
        const float* __restrict__ q, const float* __restrict__ Wk,
        const float* __restrict__ bk, short* __restrict__ u2,
        float* __restrict__ qb) {
    int et = blockIdx.x, h = blockIdx.y, c = blockIdx.z;
    int e0 = et * 64;
    __shared__ float qs[32][66];
    __shared__ float wk[64][66];
    int tid = threadIdx.x;
    int b = tid & 31, es = tid >> 5;
    for (int i = tid; i < 2048; i += 256)
        qs[i >> 6][i & 63] = q[((size_t)c * B_ + (i >> 6)) * E_ + h * 64 + (i & 63)];
    const float* W = Wk + (size_t)c * E_ * E_ + (size_t)(h * 64) * E_;
    for (int i = tid; i < 4096; i += 256)
        wk[i >> 6][i & 63] = W[(size_t)(i >> 6) * E_ + e0 + (i & 63)];
    __syncthreads();
    float acc[8] = {};
    for (int d = 0; d < 64; ++d) {
        float qv = qs[b][d];
        #pragma unroll
        for (int j = 0; j < 8; ++j)
            acc[j] += qv * wk[d][es * 8 + j];
    }
    // direct fragment-order store (old k_split_u2 math, u round-trip removed)
    int m   = b * 8 + h;
    int e0s = e0 + es * 8;
    int ks  = e0s >> 5, quad = (e0s & 31) >> 3;
    int lane = (m & 15) + 16 * quad;
    int mt  = m >> 4;
    size_t base = ((((size_t)c * 16 + mt) * 16 + ks) * 512) + (size_t)lane * 8;
    s8_t vh, vm;
    #pragma unroll
    for (int j = 0; j < 8; ++j) {
        float xv = acc[j] * 32.0f, fh, fm;
        vh[j] = (short)f16_round(xv, fh);
        vm[j] = (short)f16_round(xv - fh, fm);
    }
    *(s8_t*)(u2 + base)       = vh;
    *(s8_t*)(u2 + U2P + base) = vm;
    if (et == 0 && es == 0) {
        float s = 0.f;
        const float* bkr = bk + c * E_ + h * 64;
        for (int d = 0; d < 64; ++d) s += qs[b][d] * bkr[d];
        qb[c * 256 + b * 8 + h] = s;
    }
}

// ---------------------------------------------------------------------------
// Main: S(m,n) = member ? exp(SCALE*(dot/1024 + qb)) : 0, 3-product fp16x2
// (hh, hm, mh) via 16x16x32 f16 MFMA. Unchanged from R12/R13 (119-122 us,
// MfmaUtil 50, occupancy bound (256,4)). TLP is the proven lever here;
// schedule experiments were nulls (R9/R10).
// ---------------------------------------------------------------------------
__global__ __launch_bounds__(256, 4) void k_scores_mfma(
        const short* __restrict__ u2, const short* __restrict__ A2t,
        const float* __restrict__ qb, const int* __restrict__ mask,
        float* __restrict__ S, float* __restrict__ Zpart, int c0, int CB) {
    __shared__ __align__(16) short As[16384];   // one 32 KB ks2-tile (2 kh)
    __shared__ float sQb[128];
    __shared__ int   sMask[128];
    int bx = blockIdx.x;
    int x     = bx & 7;
    int rest  = bx >> 3;
    int mh    = rest & 1;          // m-half: rows [mh*128, mh*128+128)
    int rest2 = rest >> 1;
    int z     = rest2 % CB;
    int g     = rest2 / CB;
    int nc    = g * 8 + x;
    if (nc >= NC3) return;
    int c  = c0 + z;
    int tid = threadIdx.x;
    int lane = tid & 63, w = tid >> 6;
    int quad = lane >> 4, l15 = lane & 15;
    int n0 = nc * 128;

    if (tid < 128) {
        sQb[tid] = qb[c * 256 + mh * 128 + tid];
        int n = n0 + tid;
        sMask[tid] = (n < N_) ? mask[(size_t)n * C_ + c] : 0;
    }

    f32x4 acc[2][8];   // [mt][nt] — wave owns 32 rows x 128 cols
    #pragma unroll
    for (int i = 0; i < 2; ++i)
        #pragma unroll
        for (int j = 0; j < 8; ++j)
            acc[i][j] = (f32x4){0.f, 0.f, 0.f, 0.f};

    const char* tb = (const char*)A2t + (size_t)nc * 262144;

    for (int ks2 = 0; ks2 < 8; ++ks2) {
        __syncthreads();   // all waves done reading As (and covers sQb/sMask)
        // async DMA this ks2's 32 KB (two 16 KB kh tiles): 32 segs of 1024 B
        const char* src = tb + (size_t)ks2 * 32768;
        #pragma unroll
        for (int t = 0; t < 8; ++t) {
            int seg = w * 8 + t;
            GLOAD_LDS16(src + (size_t)seg * 1024 + lane * 16,
                        (char*)As + seg * 1024);
        }
        __syncthreads();   // compiler drains vmcnt(0) before barrier

        #pragma unroll
        for (int kh = 0; kh < 2; ++kh) {
            int ks = ks2 * 2 + kh;
            const short* Ab = As + kh * 8192;
            // A-fragments (u2): 4 global 16B loads, L2/LLC-resident
            h8_t af[2][2];
            #pragma unroll
            for (int mt = 0; mt < 2; ++mt) {
                int mtg = mh * 8 + w * 2 + mt;
                size_t ub = ((((size_t)c * 16 + mtg) * 16 + ks) * 512)
                            + (size_t)lane * 8;
                af[mt][0] = *(const h8_t*)(u2 + ub);
                af[mt][1] = *(const h8_t*)(u2 + U2P + ub);
            }
            // two nt-halves; sched_barrier caps b-frag hoisting (reg budget)
            #pragma unroll
            for (int half = 0; half < 2; ++half) {
                __builtin_amdgcn_sched_barrier(0);
                #pragma unroll
                for (int q4 = 0; q4 < 4; ++q4) {
                    int nt = half * 4 + q4;
                    int r = nt * 16 + l15;
                    const short* bp = Ab + r * 32 + ((quad + (r >> 1)) & 3) * 8;
                    h8_t b0 = *(const h8_t*)bp;
                    h8_t b1 = *(const h8_t*)(bp + 4096);
                    #pragma unroll
                    for (int mt = 0; mt < 2; ++mt) {
                        f32x4 a = acc[mt][nt];
                        a = MFMAH(af[mt][0], b0, a);   // hh
                        a = MFMAH(af[mt][0], b1, a);   // hm
                        a = MFMAH(af[mt][1], b0, a);   // mh
                        acc[mt][nt] = a;
                    }
                }
            }
        }
    }

    // Epilogue: unscale + bias + mask + exp, write S, fused deterministic
    // row-sums.  C/D: col = lane&15, row = quad*4 + r (m89/m91).
    float* Sc = S + (size_t)z * SSZ;
    #pragma unroll
    for (int mt = 0; mt < 2; ++mt) {
        float rs[4] = {0.f, 0.f, 0.f, 0.f};
        #pragma unroll
        for (int nt = 0; nt < 8; ++nt) {
            int nl = nt * 16 + l15;
            int n = n0 + nl;
            int mem = sMask[nl];
            #pragma unroll
            for (int r = 0; r < 4; ++r) {
                int ml = w * 32 + mt * 16 + quad * 4 + r;   // local row in half
                float sc = SCALE * (acc[mt][nt][r] * UNSC + sQb[ml]);
                float ev = mem ? __expf(sc) : 0.f;
                rs[r] += ev;
                if (n < N_) Sc[(size_t)(mh * 128 + ml) * N_ + n] = ev;
            }
        }
        #pragma unroll
        for (int r = 0; r < 4; ++r) {
            float v = rs[r];
            v += __shfl_xor(v, 1); v += __shfl_xor(v, 2);
            v += __shfl_xor(v, 4); v += __shfl_xor(v, 8);
            if (l15 == 0) {
                int ml = w * 32 + mt * 16 + quad * 4 + r;
                Zpart[((size_t)nc * C_ + c) * 256 + mh * 128 + ml] = v;
            }
        }
    }
}

// ---------------------------------------------------------------------------
// K3 (R15): fully fused [Z-sum + head-average + chunk top-ns + final merge].
// grid (B, CB), block 640 = 10 waves; wave w owns chunks {2w, 2w+1}.
// Z: parallel across all 64 lanes (lane = slice*8 + h; 8 slices of ~20 nc
// each, then xor-shfl tree over the slice bits — pairwise sums commute, so
// all lanes get bitwise-identical Z). Replaces the 157-long 8-lane serial
// chain of R14 (latency-bound prefix, ~10 us).
// Per chunk: 16 values/lane in registers, ns rounds of {16-slot local scan
// -> 64-lane butterfly -> in-register removal} (identical tie-break to
// jax top_k: value desc, index asc). Winners -> 800 B LDS; wave 0 then runs
// the exact old-topk2 merge over the 100 candidates (same flat order,
// same compare), writing the final output. Kills k_topk2 + cand round-trip.
// ---------------------------------------------------------------------------
__global__ __launch_bounds__(640) void k_topk(
        const float* __restrict__ S, const float* __restrict__ Zpart,
        float* __restrict__ out, int c0, int ns) {
    int b = blockIdx.x, z = blockIdx.y;
    int c = c0 + z;
    int tid = threadIdx.x;
    int lane = tid & 63, w = tid >> 6;   // w in 0..9
    const float* Sc = S + (size_t)z * SSZ;

    __shared__ float2 wcand[NCH * 8];    // [chunk*ns + j], ns <= 8

    // ---- Z (all 64 lanes): h = lane&7, slice = lane>>3 over nc ----
    float zrl;
    {
        int h = lane & 7, sl = lane >> 3;
        const float* zp = Zpart + (size_t)c * 256 + b * 8 + h;
        float s = 0.f;
        for (int nc = sl; nc < NC3; nc += 8)
            s += zp[(size_t)nc * (C_ * 256)];
        s += __shfl_xor(s, 8, 64);
        s += __shfl_xor(s, 16, 64);
        s += __shfl_xor(s, 32, 64);
        zrl = 0.125f / s;
    }
    float zr[H_];
    #pragma unroll
    for (int h = 0; h < H_; ++h) zr[h] = __shfl(zrl, h, 64);

    // ---- per-wave: 2 chunks sequentially ----
    for (int p = 0; p < 2; ++p) {
        int chunk = w * 2 + p;
        int base = chunk * CHUNK + lane * 4;   // slot s=j*4+t -> n=base+j*256+t
        float va[16];
        #pragma unroll
        for (int s = 0; s < 16; ++s) va[s] = 0.f;
        bool ok[4];
        #pragma unroll
        for (int j = 0; j < 4; ++j) ok[j] = (base + j * 256) < N_;  // N_%4==0

        #pragma unroll
        for (int h = 0; h < H_; ++h) {
            const float* row = Sc + (size_t)(b * H_ + h) * N_;
            float wz = zr[h];
            #pragma unroll
            for (int j = 0; j < 4; ++j) {
                if (ok[j]) {
                    const float4 sv = *(const float4*)&row[base + j * 256];
                    va[j * 4 + 0] += sv.x * wz;
                    va[j * 4 + 1] += sv.y * wz;
                    va[j * 4 + 2] += sv.z * wz;
                    va[j * 4 + 3] += sv.w * wz;
                }
            }
        }
        #pragma unroll
        for (int j = 0; j < 4; ++j)
            if (!ok[j]) {
                va[j * 4 + 0] = -1.f; va[j * 4 + 1] = -1.f;
                va[j * 4 + 2] = -1.f; va[j * 4 + 3] = -1.f;
            }

        for (int j = 0; j < ns; ++j) {
            // local max over 16 slots; ascending scan + strict > = lowest n
            float bv = va[0]; int bs = 0;
            #pragma unroll
            for (int s = 1; s < 16; ++s)
                if (va[s] > bv) { bv = va[s]; bs = s; }
            int bn = ok[bs >> 2] ? (base + ((bs >> 2) << 8) + (bs & 3)) : N_;
            // 64-lane butterfly (all lanes converge on wave winner)
            #pragma unroll
            for (int off = 1; off < 64; off <<= 1) {
                float ov = __shfl_xor(bv, off, 64);
                int   on = __shfl_xor(bn, off, 64);
                if (ov > bv || (ov == bv && on < bn)) { bv = ov; bn = on; }
            }
            if (lane == 0) wcand[chunk * ns + j] = make_float2(bv, (float)bn);
            // in-register removal: only the owner lane matches bn
            #pragma unroll
            for (int s = 0; s < 16; ++s) {
                int n_s = base + ((s >> 2) << 8) + (s & 3);
                if (n_s == bn) va[s] = -2.f;
            }
        }
    }
    __syncthreads();

    // ---- wave 0: merge 100 candidates (exact old-topk2 semantics) ----
    if (w == 0) {
        int ncand = NCH * ns;   // 100
        float v0 = -3.f, v1 = -3.f;
        int   i0 = N_ + 1, i1 = N_ + 2;
        if (lane < ncand)      { float2 e = wcand[lane];      v0 = e.x; i0 = (int)e.y; }
        if (lane + 64 < ncand) { float2 e = wcand[lane + 64]; v1 = e.x; i1 = (int)e.y; }
        for (int j = 0; j < ns; ++j) {
            float bv = v0; int bn = i0;
            if (v1 > bv || (v1 == bv && i1 < bn)) { bv = v1; bn = i1; }
            #pragma unroll
            for (int off = 1; off < 64; off <<= 1) {
                float ov = __shfl_xor(bv, off, 64);
                int   on = __shfl_xor(bn, off, 64);
                if (ov > bv || (ov == bv && on < bn)) { bv = ov; bn = on; }
            }
            if (lane == 0) {
                out[((size_t)b * C_ + c) * ns + j] = (float)bn;
                out[(size_t)B_ * C_ * ns + ((size_t)b * C_ + c) * ns + j] = bv;
            }
            if (i0 == bn) v0 = -3.f;
            if (i1 == bn) v1 = -3.f;
        }
    }
}

// ---------------------------------------------------------------------------
extern "C" void kernel_launch(void* const* d_in, const int* in_sizes, int n_in,
                              void* d_out, int out_size, void* d_ws, size_t ws_size,
                              hipStream_t stream) {
    const float* x    = (const float*)d_in[0];  // (B,E)
    const float* A    = (const float*)d_in[1];  // (N,E)
    const int*   mask = (const int*)  d_in[2];  // (N,C)
    const float* Wq   = (const float*)d_in[3];  // (C,E,E)
    const float* bq   = (const float*)d_in[4];  // (C,E)
    const float* Wk   = (const float*)d_in[5];  // (C,E,E)
    const float* bk   = (const float*)d_in[6];  // (C,E)
    float* out = (float*)d_out;

    int ns = out_size / (2 * B_ * C_);          // = n_samples (5)

    // Workspace carve (floats) — u, Z, cand buffers removed
    float* ws = (float*)d_ws;
    float* q     = ws;                                    // 131072
    float* qb    = q     + (size_t)C_ * B_ * E_;          // 2048
    float* Zpart = qb    + (size_t)C_ * B_ * H_;          // NC3*8*256 = 321536
    short* u2    = (short*)(Zpart + (size_t)NC3 * C_ * 256);   // 2*1048576 shorts
    short* A2t   = u2 + 2 * U2P;                               // NC3*16*8192 shorts
    float* S     = (float*)(A2t + (size_t)NC3 * 16 * 8192);
    size_t fixedFloats = (size_t)(S - ws);

    int CB = 8;
    while (CB > 1 && (fixedFloats + (size_t)CB * SSZ + 16) * 4 > ws_size)
        CB >>= 1;

    k_prep<<<NC3 * 16 + 512, 256, 0, stream>>>(A, A2t, x, Wq, bq, q);
    k_u2<<<dim3(8, H_, C_), 256, 0, stream>>>(q, Wk, bk, u2, qb);

    for (int c0 = 0; c0 < C_; c0 += CB) {
        // grid: (g, z, mh, x) packed; 2 m-half blocks per (nc, c)
        k_scores_mfma<<<NCG * 2 * 8 * CB, 256, 0, stream>>>(u2, A2t, qb, mask, S, Zpart, c0, CB);
        k_topk<<<dim3(B_, CB), 640, 0, stream>>>(S, Zpart, out, c0, ns);
    }
}